// Round 3
// baseline (170.593 us; speedup 1.0000x reference)
//
#include <hip/hip_runtime.h>
#include <math.h>

// DirectionalContrastiveLoss — N=8, C=192, H=W=112, T=0.1
//
// R3: barrier-free direct-from-global scheme. Each thread owns 2 x-adjacent
// pixels (even col j, j+1) and a 48-channel slice (C-split x4, lanes q=0..3
// within a wave). Per channel it loads the 3x4 window (3 float2 + 6 float),
// accumulates 18 neighbor dots + 12 window sum-of-squares in registers.
// Channel quarters are combined with two shfl_xor butterflies; all norms are
// available locally (no LDS tiles, no __syncthreads in hot loop). 3136 waves
// = 12.25/CU of independent work vs R2's 224 barrier-coupled blocks.

namespace {
constexpr int N_ = 8, C_ = 192, H_ = 112, W_ = 112;
constexpr int HW = H_ * W_;
constexpr int WP = W_ / 2;                       // 56 pair-cols
constexpr int PAIRS_IMG = H_ * WP;               // 6272
constexpr int TOTAL_PAIRS = N_ * PAIRS_IMG;      // 50176
constexpr int CSPLIT = 4;
constexpr int CPT = C_ / CSPLIT;                 // 48 channels per thread
constexpr int NT = 256;
constexpr int NBLK = TOTAL_PAIRS * CSPLIT / NT;  // 784 blocks
constexpr float INV_T = 10.0f;
constexpr double TOTAL = (double)N_ * N_ * H_ * W_;  // 802816
}

__device__ __forceinline__ float sel3(int d, float a, float b, float c) {
    float r = (d < 0) ? a : b;
    return (d > 0) ? c : r;
}

__device__ __forceinline__ float px_loss(
    float l00, float l01, float l02,
    float l10, float l11, float l12,
    float l20, float l21, float l22,
    int gi, int gj, int n,
    const int* __restrict__ labels, const int* __restrict__ dirs)
{
    const int pix = gi * W_ + gj;
    float denom = 0.f, sumlog = 0.f;
#pragma unroll
    for (int m = 0; m < N_; ++m) {
        int d0 = dirs[((m * 2 + 0) * H_ + gi) * W_ + gj];
        int d1 = dirs[((m * 2 + 1) * H_ + gi) * W_ + gj];
        float r0 = sel3(d1, l00, l01, l02);
        float r1 = sel3(d1, l10, l11, l12);
        float r2 = sel3(d1, l20, l21, l22);
        float lm = sel3(d0, r0, r1, r2);
        int labm = labels[m * HW + pix];
        int labn = labels[n * HW + (gi + d0) * W_ + (gj + d1)];
        bool msk = (labm == labn);
        float e = msk ? __expf(lm) : 0.f;
        denom += e;
        sumlog += msk ? lm : -INFINITY;
    }
    return 8.0f * __logf(denom + 1e-6f) - sumlog;
}

#define COMB(x) { x += __shfl_xor(x, 16, 64); x += __shfl_xor(x, 32, 64); }

extern "C" __global__ void __launch_bounds__(NT)
dcl_main(const float* __restrict__ feat,
         const int* __restrict__ labels,
         const int* __restrict__ dirs,
         double* __restrict__ partial, int use_partial)
{
    const int tid  = threadIdx.x;
    const int lane = tid & 63;
    const int wv   = tid >> 6;
    const int q    = lane >> 4;                         // channel quarter 0..3
    const int pi   = (blockIdx.x * 4 + wv) * 16 + (lane & 15);  // pair index

    const int n  = pi / PAIRS_IMG;                      // uniform per 16-lane group
    const int rm = pi - n * PAIRS_IMG;
    const int gi = rm / WP;
    const int j  = (rm - gi * WP) * 2;                  // even col -> 8B aligned

    const int cl = max(j - 1, 0);
    const int cr = min(j + 2, W_ - 1);
    const int rowo0 = max(gi - 1, 0) * W_;
    const int rowo1 = gi * W_;
    const int rowo2 = min(gi + 1, H_ - 1) * W_;

    const float* __restrict__ base = feat + ((size_t)n * C_ + (size_t)q * CPT) * HW;

    float sA[3][3] = {{0.f}};   // dots for px (gi, j),   neighbor cols j-1..j+1
    float sB[3][3] = {{0.f}};   // dots for px (gi, j+1), neighbor cols j..j+2
    float ssv[3][4] = {{0.f}};  // sum-squares, window cols j-1, j, j+1, j+2

#pragma unroll 2
    for (int c = 0; c < CPT; ++c) {
        const float* __restrict__ pc = base + (size_t)c * HW;
        float2 m0 = *(const float2*)(pc + rowo0 + j);
        float2 m1 = *(const float2*)(pc + rowo1 + j);
        float2 m2 = *(const float2*)(pc + rowo2 + j);
        float lf0 = pc[rowo0 + cl], lf1 = pc[rowo1 + cl], lf2 = pc[rowo2 + cl];
        float rg0 = pc[rowo0 + cr], rg1 = pc[rowo1 + cr], rg2 = pc[rowo2 + cr];
        float a = m1.x, b = m1.y;
        sA[0][0] += a*lf0;  sA[0][1] += a*m0.x; sA[0][2] += a*m0.y;
        sA[1][0] += a*lf1;  sA[1][1] += a*m1.x; sA[1][2] += a*m1.y;
        sA[2][0] += a*lf2;  sA[2][1] += a*m2.x; sA[2][2] += a*m2.y;
        sB[0][0] += b*m0.x; sB[0][1] += b*m0.y; sB[0][2] += b*rg0;
        sB[1][0] += b*m1.x; sB[1][1] += b*m1.y; sB[1][2] += b*rg1;
        sB[2][0] += b*m2.x; sB[2][1] += b*m2.y; sB[2][2] += b*rg2;
        ssv[0][0] += lf0*lf0; ssv[0][1] += m0.x*m0.x; ssv[0][2] += m0.y*m0.y; ssv[0][3] += rg0*rg0;
        ssv[1][0] += lf1*lf1; ssv[1][1] += m1.x*m1.x; ssv[1][2] += m1.y*m1.y; ssv[1][3] += rg1*rg1;
        ssv[2][0] += lf2*lf2; ssv[2][1] += m2.x*m2.x; ssv[2][2] += m2.y*m2.y; ssv[2][3] += rg2*rg2;
    }

    // ---- combine the 4 channel quarters (butterfly: all lanes get full sums)
#pragma unroll
    for (int r2_ = 0; r2_ < 3; ++r2_) {
#pragma unroll
        for (int c2_ = 0; c2_ < 3; ++c2_) { COMB(sA[r2_][c2_]); COMB(sB[r2_][c2_]); }
#pragma unroll
        for (int c2_ = 0; c2_ < 4; ++c2_) { COMB(ssv[r2_][c2_]); }
    }

    // ---- epilogue on quarter-0 lanes only
    float lp = 0.f;
    if (q == 0) {
        float inv[3][4];
#pragma unroll
        for (int r2_ = 0; r2_ < 3; ++r2_)
#pragma unroll
            for (int c2_ = 0; c2_ < 4; ++c2_)
                inv[r2_][c2_] = 1.0f / fmaxf(sqrtf(ssv[r2_][c2_]), 1e-12f);
        const float iA = inv[1][1] * INV_T;
        const float iB = inv[1][2] * INV_T;
        lp  = px_loss(sA[0][0]*iA*inv[0][0], sA[0][1]*iA*inv[0][1], sA[0][2]*iA*inv[0][2],
                      sA[1][0]*iA*inv[1][0], sA[1][1]*iA*inv[1][1], sA[1][2]*iA*inv[1][2],
                      sA[2][0]*iA*inv[2][0], sA[2][1]*iA*inv[2][1], sA[2][2]*iA*inv[2][2],
                      gi, j, n, labels, dirs);
        lp += px_loss(sB[0][0]*iB*inv[0][1], sB[0][1]*iB*inv[0][2], sB[0][2]*iB*inv[0][3],
                      sB[1][0]*iB*inv[1][1], sB[1][1]*iB*inv[1][2], sB[1][2]*iB*inv[1][3],
                      sB[2][0]*iB*inv[2][1], sB[2][1]*iB*inv[2][2], sB[2][2]*iB*inv[2][3],
                      gi, j + 1, n, labels, dirs);
    }

    // ---- wave + block reduction
#pragma unroll
    for (int off = 32; off > 0; off >>= 1) lp += __shfl_down(lp, off, 64);
    __shared__ float red[NT / 64];
    if (lane == 0) red[wv] = lp;
    __syncthreads();
    if (tid == 0) {
        float s = red[0] + red[1] + red[2] + red[3];
        if (use_partial) partial[blockIdx.x] = (double)s;
        else atomicAdd(partial, (double)s);
    }
}

extern "C" __global__ void __launch_bounds__(256)
dcl_final(const double* __restrict__ partial, float* __restrict__ out, int nblk)
{
    const int tid = threadIdx.x;
    double s = 0.0;
    for (int i = tid; i < nblk; i += 256) s += partial[i];
#pragma unroll
    for (int off = 32; off > 0; off >>= 1) s += __shfl_down(s, off, 64);
    __shared__ double red[4];
    const int lane = tid & 63, wv = tid >> 6;
    if (lane == 0) red[wv] = s;
    __syncthreads();
    if (tid == 0) out[0] = (float)((red[0] + red[1] + red[2] + red[3]) / TOTAL);
}

extern "C" void kernel_launch(void* const* d_in, const int* in_sizes, int n_in,
                              void* d_out, int out_size, void* d_ws, size_t ws_size,
                              hipStream_t stream) {
    const float* feat   = (const float*)d_in[0];
    const int*   labels = (const int*)d_in[1];
    const int*   dirs   = (const int*)d_in[2];
    double* acc = (double*)d_ws;
    float*  out = (float*)d_out;

    const int use_partial = (ws_size >= (size_t)NBLK * sizeof(double)) ? 1 : 0;
    if (!use_partial) hipMemsetAsync(acc, 0, sizeof(double), stream);
    dcl_main<<<NBLK, NT, 0, stream>>>(feat, labels, dirs, acc, use_partial);
    dcl_final<<<1, 256, 0, stream>>>(acc, out, use_partial ? NBLK : 1);
}